// Round 3
// baseline (501.457 us; speedup 1.0000x reference)
//
#include <hip/hip_runtime.h>
#include <hip/hip_bf16.h>

typedef float f32x4 __attribute__((ext_vector_type(4)));
typedef short s16x8 __attribute__((ext_vector_type(8)));

using bf16 = __hip_bfloat16;

namespace {
constexpr int KD = 1024;      // 8 * C_IN
constexpr int BK = 32;        // K per MFMA step
constexpr int NT = KD / BK;   // 32
}

__device__ __forceinline__ s16x8 cvt8(f32x4 a, f32x4 b) {
  union { s16x8 v; bf16 h[8]; } u;
#pragma unroll
  for (int j = 0; j < 4; ++j) u.h[j] = __float2bfloat16(a[j]);
#pragma unroll
  for (int j = 0; j < 4; ++j) u.h[j + 4] = __float2bfloat16(b[j]);
  return u.v;
}

// weights [1024][256] fp32 -> Bt [256][1024] bf16 (transposed, MFMA-B friendly)
__global__ void k_transpose_w(const float* __restrict__ w, bf16* __restrict__ bt) {
  int t = blockIdx.x * 256 + threadIdx.x;   // 32768 threads
  int n = t & 255;
  int k0 = (t >> 8) << 3;
  union { s16x8 v; bf16 h[8]; } u;
#pragma unroll
  for (int j = 0; j < 8; ++j)
    u.h[j] = __float2bfloat16(w[(size_t)(k0 + j) * 256 + n]);
  *(s16x8*)(bt + (size_t)n * KD + k0) = u.v;
}

__global__ void k_clear_flags(int* __restrict__ flags, int np4) {
  int i = blockIdx.x * 256 + threadIdx.x;
  if (i < np4) ((int4*)flags)[i] = make_int4(0, 0, 0, 0);
}

__global__ void k_set_flags(const int* __restrict__ idx, int* __restrict__ flags, int m) {
  int i = blockIdx.x * 256 + threadIdx.x;
  if (i < m) flags[idx[i]] = 1;
}

// Fused GEMM + zero-fill. NO LDS, NO barriers: each wave owns a 64(M)x64(N)
// output tile, loads A fragments straight from global (fp32, cvt->bf16 in
// regs; 4 sibling waves in a block share A rows via L1/L2) and B fragments
// from the L2-resident transposed weights. Every 5th block instead zeros
// the empty parent rows (disjoint from GEMM-written rows -> order-free).
__global__ __launch_bounds__(256, 3)
void k_fused(const float* __restrict__ A, const bf16* __restrict__ Bt,
             const int* __restrict__ idx, const int* __restrict__ flags,
             float* __restrict__ out, int NP, int ZBtot) {
  const int bid = blockIdx.x;
  const int lane = threadIdx.x & 63;
  const int wave = threadIdx.x >> 6;   // 0..3

  if ((bid % 5) == 4) {                // ---- zero-fill path ----
    const int zb = bid / 5;            // 0..ZBtot-1
    const f32x4 z = {0.f, 0.f, 0.f, 0.f};
    const int stride = ZBtot * 4;
    for (int row = zb * 4 + wave; row < NP; row += stride) {
      if (flags[row] == 0)
        *(f32x4*)(out + (size_t)row * 256 + lane * 4) = z;
    }
    return;
  }

  // ---- GEMM path ----
  const int gid = bid - bid / 5;       // 0..MT-1 (64-row tile)
  const size_t m0 = (size_t)gid * 64;
  const int n0 = wave * 64;

  // 16x16x32 fragment ownership: row = lane&15, k-octet = lane>>4
  const int r = lane & 15;
  const int kc = lane >> 4;

  const float* ap = A + (m0 + r) * KD + kc * 8;             // A[m0+r][kc*8]
  const bf16*  bp = Bt + (size_t)(n0 + r) * KD + kc * 8;    // Bt[n0+r][kc*8]

  f32x4 acc[4][4] = {};

#pragma unroll 2
  for (int t = 0; t < NT; ++t) {
    s16x8 bv[4], av[4];
#pragma unroll
    for (int fn = 0; fn < 4; ++fn)
      bv[fn] = *(const s16x8*)(bp + (size_t)fn * 16 * KD + t * BK);
#pragma unroll
    for (int fm = 0; fm < 4; ++fm) {
      f32x4 lo = *(const f32x4*)(ap + (size_t)fm * 16 * KD + t * BK);
      f32x4 hi = *(const f32x4*)(ap + (size_t)fm * 16 * KD + t * BK + 4);
      av[fm] = cvt8(lo, hi);
    }
#pragma unroll
    for (int fm = 0; fm < 4; ++fm)
#pragma unroll
      for (int fn = 0; fn < 4; ++fn)
        acc[fm][fn] = __builtin_amdgcn_mfma_f32_16x16x32_bf16(
            av[fm], bv[fn], acc[fm][fn], 0, 0, 0);
  }

  // ---- epilogue: C/D layout col = lane&15, row = (lane>>4)*4 + j ----
  const int col0 = n0 + r;
#pragma unroll
  for (int fm = 0; fm < 4; ++fm) {
    const int4 rows = *(const int4*)(idx + m0 + fm * 16 + kc * 4);
    const int rj[4] = {rows.x, rows.y, rows.z, rows.w};
#pragma unroll
    for (int j = 0; j < 4; ++j) {
      float* op = out + (size_t)rj[j] * 256 + col0;
#pragma unroll
      for (int fn = 0; fn < 4; ++fn)
        op[fn * 16] = acc[fm][fn][j];
    }
  }
}

extern "C" void kernel_launch(void* const* d_in, const int* in_sizes, int n_in,
                              void* d_out, int out_size, void* d_ws, size_t ws_size,
                              hipStream_t stream) {
  const float* data = (const float*)d_in[0];   // [N, 128] == [M, 1024]
  const float* w    = (const float*)d_in[1];   // [8,128,256] == [1024, 256]
  const int*   idx  = (const int*)d_in[2];     // [M] sorted unique parent slots
  float* out = (float*)d_out;                  // [NP, 256]

  const int M  = in_sizes[2];        // 131072
  const int NP = out_size / 256;     // 262144

  int* flags = (int*)d_ws;                                    // NP ints (1 MB)
  bf16* bt = (bf16*)((char*)d_ws + (size_t)NP * sizeof(int)); // 512 KB

  const int MT = M / 64;             // 2048 GEMM tiles
  const int ZB = MT / 4;             // 512 zeroer blocks (every 5th block)
  const int TOT = MT + ZB;           // 2560

  k_transpose_w<<<128, 256, 0, stream>>>(w, bt);
  k_clear_flags<<<(NP / 4 + 255) / 256, 256, 0, stream>>>(flags, NP / 4);
  k_set_flags<<<(M + 255) / 256, 256, 0, stream>>>(idx, flags, M);
  k_fused<<<TOT, 256, 0, stream>>>(data, bt, idx, flags, out, NP, ZB);
}

// Round 4
// 249.734 us; speedup vs baseline: 2.0080x; 2.0080x over previous
//
#include <hip/hip_runtime.h>
#include <hip/hip_bf16.h>

typedef float f32x4 __attribute__((ext_vector_type(4)));
typedef short s16x8 __attribute__((ext_vector_type(8)));

using bf16 = __hip_bfloat16;

namespace {
constexpr int KD = 1024;            // 8 * C_IN
constexpr int BM = 128;
constexpr int BK = 32;
constexpr int NT = KD / BK;         // 32 K-tiles
constexpr int MBLK = 131072 / BM;   // 1024 GEMM blocks
constexpr int ZBLK = 512;           // zero-fill blocks appended to the grid
}

typedef __attribute__((address_space(1))) const void GVoid;
typedef __attribute__((address_space(3))) void LVoid;

// async global->LDS DMA, 16B per lane; LDS dest = wave-uniform base + lane*16
__device__ __forceinline__ void gld16(const void* g, void* l) {
  __builtin_amdgcn_global_load_lds((GVoid*)g, (LVoid*)l, 16, 0, 0);
}

__device__ __forceinline__ s16x8 cvt8(f32x4 a, f32x4 b) {
  union { s16x8 v; bf16 h[8]; } u;
#pragma unroll
  for (int j = 0; j < 4; ++j) u.h[j] = __float2bfloat16(a[j]);
#pragma unroll
  for (int j = 0; j < 4; ++j) u.h[j + 4] = __float2bfloat16(b[j]);
  return u.v;
}

// weights [1024][256] fp32 -> Bt [256][1024] bf16 (transposed, MFMA-B friendly)
__global__ void k_transpose_w(const float* __restrict__ w, bf16* __restrict__ bt) {
  int t = blockIdx.x * 256 + threadIdx.x;   // 32768 threads
  int n = t & 255;
  int k0 = (t >> 8) << 3;
  union { s16x8 v; bf16 h[8]; } u;
#pragma unroll
  for (int j = 0; j < 8; ++j)
    u.h[j] = __float2bfloat16(w[(size_t)(k0 + j) * 256 + n]);
  *(s16x8*)(bt + (size_t)n * KD + k0) = u.v;
}

__global__ void k_clear_flags(int* __restrict__ flags, int np4) {
  int i = blockIdx.x * 256 + threadIdx.x;
  if (i < np4) ((int4*)flags)[i] = make_int4(0, 0, 0, 0);
}

__global__ void k_set_flags(const int* __restrict__ idx, int* __restrict__ flags, int m) {
  int i = blockIdx.x * 256 + threadIdx.x;
  if (i < m) flags[idx[i]] = 1;
}

// Fused GEMM + zero-fill. GEMM: A fp32 + B bf16 staged via global_load_lds,
// double-buffered with COUNTED vmcnt (never 0 in steady state) + raw
// s_barrier — no __syncthreads vmcnt(0) drain, so tile t+1's DMA stays in
// flight across the whole compute phase (T3/T4). Blocks >= MBLK zero the
// empty parent rows (disjoint from GEMM-written rows -> order-free).
__global__ __launch_bounds__(512, 2)
void k_fused(const float* __restrict__ A, const bf16* __restrict__ Bt,
             const int* __restrict__ idx, const int* __restrict__ flags,
             float* __restrict__ out, int NP) {
  __shared__ float As[2][BM * BK];    // 2 x 16 KB fp32
  __shared__ bf16  Bs[2][256 * BK];   // 2 x 16 KB bf16

  const int tid = threadIdx.x;
  const int lane = tid & 63;
  const int wave = tid >> 6;          // 0..7

  if (blockIdx.x >= MBLK) {           // ---- zero-fill path ----
    const int zb = blockIdx.x - MBLK;
    const f32x4 z = {0.f, 0.f, 0.f, 0.f};
    for (int row = zb * 8 + wave; row < NP; row += ZBLK * 8) {
      if (flags[row] == 0)
        *(f32x4*)(out + (size_t)row * 256 + lane * 4) = z;
    }
    return;
  }

  // ---- GEMM path ----
  const int m0 = blockIdx.x * BM;
  const int wm = wave >> 2;           // 0..1 (row half)
  const int wn = wave & 3;            // 0..3 (col quarter)

  // Staging: LDS filled LINEARLY in 16B chunks (gld16 requirement); the
  // swizzle lives in the per-lane GLOBAL source address (rule #21).
  // A: 1024 chunks (row stride 8 chunks), swizzle c^(row&6) (pair-aligned).
  const int as0 = tid, as1 = 512 + tid;
  const int ar0 = as0 >> 3, ac0 = (as0 & 7) ^ (ar0 & 6);
  const int ar1 = as1 >> 3, ac1 = (as1 & 7) ^ (ar1 & 6);
  const float* aSrc0 = A + (size_t)(m0 + ar0) * KD + ac0 * 4;
  const float* aSrc1 = A + (size_t)(m0 + ar1) * KD + ac1 * 4;
  const int aOff0 = (wave * 64) * 4;          // f32 index of wave's chunk run
  const int aOff1 = (512 + wave * 64) * 4;

  // B: 1024 chunks (row stride 4 chunks), swizzle c^(row&3).
  const int bs0 = tid, bs1 = 512 + tid;
  const int br0 = bs0 >> 2, bc0 = (bs0 & 3) ^ (br0 & 3);
  const int br1 = bs1 >> 2, bc1 = (bs1 & 3) ^ (br1 & 3);
  const bf16* bSrc0 = Bt + (size_t)br0 * KD + bc0 * 8;
  const bf16* bSrc1 = Bt + (size_t)br1 * KD + bc1 * 8;
  const int bOff0 = (wave * 64) * 8;          // bf16 index
  const int bOff1 = (512 + wave * 64) * 8;

  // Fragment read offsets (16x16x32: lane -> row l&15, k-octet l>>4), with
  // the same swizzle applied on the read side; fm/fn row-stride 16 keeps the
  // swizzle bits invariant so the fragment stride is a constant 512 elems.
  const int arow = wm * 64 + (lane & 15);
  const int kc = lane >> 4;
  const int aRd = arow * 32 + (((2 * kc) ^ (arow & 6)) * 4);  // f32 idx
  const int brow = wn * 64 + (lane & 15);
  const int bRd = brow * 32 + ((kc ^ (brow & 3)) * 8);        // bf16 idx

  f32x4 acc[4][4] = {};

  auto stage = [&](int buf, int t) {
    gld16(aSrc0 + t * BK, &As[buf][aOff0]);
    gld16(aSrc1 + t * BK, &As[buf][aOff1]);
    gld16(bSrc0 + t * BK, &Bs[buf][bOff0]);
    gld16(bSrc1 + t * BK, &Bs[buf][bOff1]);
  };

  stage(0, 0);   // 4 loads outstanding

  int cur = 0;
#pragma unroll 1
  for (int t = 0; t < NT; ++t) {
    if (t + 1 < NT) {
      // Buffer cur^1 was last read in iter t-1; its readers all passed the
      // bottom barrier of iter t-1 before any wave reaches this point.
      stage(cur ^ 1, t + 1);                       // 8 outstanding
      asm volatile("s_waitcnt vmcnt(4)" ::: "memory");  // tile t landed,
                                                        // tile t+1 in flight
    } else {
      asm volatile("s_waitcnt vmcnt(0)" ::: "memory");  // final tile
    }
    __builtin_amdgcn_s_barrier();   // all waves' tile-t DMA visible
    asm volatile("" ::: "memory");

    s16x8 bfr[4];
#pragma unroll
    for (int fn = 0; fn < 4; ++fn)
      bfr[fn] = *(const s16x8*)(&Bs[cur][bRd + fn * 512]);

#pragma unroll
    for (int fm = 0; fm < 4; ++fm) {
      f32x4 lo = *(const f32x4*)(&As[cur][aRd + fm * 512]);
      f32x4 hi = *(const f32x4*)(&As[cur][aRd + fm * 512 + 4]);
      s16x8 af = cvt8(lo, hi);
#pragma unroll
      for (int fn = 0; fn < 4; ++fn)
        acc[fm][fn] = __builtin_amdgcn_mfma_f32_16x16x32_bf16(
            af, bfr[fn], acc[fm][fn], 0, 0, 0);
    }

    asm volatile("" ::: "memory");
    __builtin_amdgcn_s_barrier();   // reads of buf cur done -> reusable
    cur ^= 1;
  }

  // ---- epilogue: C/D layout col = lane&15, row = (lane>>4)*4 + j ----
  const int col0 = wn * 64 + (lane & 15);
  const int rb = m0 + wm * 64 + (kc << 2);
#pragma unroll
  for (int fm = 0; fm < 4; ++fm) {
    const int4 rows = *(const int4*)(idx + rb + fm * 16);
    const int rj[4] = {rows.x, rows.y, rows.z, rows.w};
#pragma unroll
    for (int j = 0; j < 4; ++j) {
      float* op = out + (size_t)rj[j] * 256 + col0;
#pragma unroll
      for (int fn = 0; fn < 4; ++fn)
        op[fn * 16] = acc[fm][fn][j];
    }
  }
}

extern "C" void kernel_launch(void* const* d_in, const int* in_sizes, int n_in,
                              void* d_out, int out_size, void* d_ws, size_t ws_size,
                              hipStream_t stream) {
  const float* data = (const float*)d_in[0];   // [N, 128] == [M, 1024]
  const float* w    = (const float*)d_in[1];   // [8,128,256] == [1024, 256]
  const int*   idx  = (const int*)d_in[2];     // [M] sorted unique parent slots
  float* out = (float*)d_out;                  // [NP, 256]

  const int M  = in_sizes[2];        // 131072
  const int NP = out_size / 256;     // 262144

  int* flags = (int*)d_ws;                                    // NP ints (1 MB)
  bf16* bt = (bf16*)((char*)d_ws + (size_t)NP * sizeof(int)); // 512 KB

  k_transpose_w<<<128, 256, 0, stream>>>(w, bt);
  k_clear_flags<<<(NP / 4 + 255) / 256, 256, 0, stream>>>(flags, NP / 4);
  k_set_flags<<<(M + 255) / 256, 256, 0, stream>>>(idx, flags, M);
  k_fused<<<MBLK + ZBLK, 512, 0, stream>>>(data, bt, idx, flags, out, NP);
}